// Round 1
// baseline (477.640 us; speedup 1.0000x reference)
//
#include <hip/hip_runtime.h>
#include <math.h>

// Problem constants (reference: B=64, L=512, H=512, LOC_SIZE=100000)
constexpr int NB = 64;
constexpr int NL = 512;
constexpr int NH = 512;
#define EPSV 1e-9f

// Workspace layout (floats):
//   S   : 4 * NH * NB   (S_t[arr][h][b], arr = {ca, cb, da, db})  -- zeroed each launch
//   Vc  : NH * NB       (Vc_t[k][b])
//   Vd  : NH * NB       (Vd_t[k][b])
//   lg  : NH * NB       (logits_t[j][b])

// ---------------------------------------------------------------------------
// K1: masked, coefficient-weighted gather-reduce over L.
// grid = (NL/64, NB), block = 256. Thread (hi, ls): h-range hi*4..hi*4+3,
// l stride 2 starting at l0+ls. float4 row loads are coalesced (1 KB/wave).
// ---------------------------------------------------------------------------
__global__ __launch_bounds__(256) void k1_gather(
    const float* __restrict__ td_u, const float* __restrict__ td_l,
    const float* __restrict__ ld_u, const float* __restrict__ ld_l,
    const int* __restrict__ cur_loc, const int* __restrict__ loc_len,
    const float* __restrict__ locw, float* __restrict__ S)
{
    const int b   = blockIdx.y;
    const int len = loc_len[b];
    const int l0  = blockIdx.x * 64;
    if (l0 >= len) return;
    const int l1  = min(l0 + 64, len);

    const int tid = threadIdx.x;
    const int hi  = tid & 127;   // h-group index (4 floats each)
    const int ls  = tid >> 7;    // 0 or 1: which l parity this thread handles

    float acc[4][4];
#pragma unroll
    for (int a = 0; a < 4; ++a)
#pragma unroll
        for (int e = 0; e < 4; ++e) acc[a][e] = 0.f;

#pragma unroll 4
    for (int l = l0 + ls; l < l1; l += 2) {
        const int off = b * NL + l;
        const float tu = td_u[off], tl = td_l[off];
        const float lu = ld_u[off], ll = ld_l[off];
        const float rt = 1.f / (tu + tl + EPSV);
        const float rl = 1.f / (lu + ll + EPSV);
        const float a_ = tu * rt, b_ = tl * rt;
        const float c_ = lu * rl, d_ = ll * rl;
        const float w[4] = { c_ * a_, c_ * b_, d_ * a_, d_ * b_ };
        const int idx = cur_loc[off];
        const float4 x = *(const float4*)(locw + (size_t)idx * NH + hi * 4);
#pragma unroll
        for (int a = 0; a < 4; ++a) {
            acc[a][0] += w[a] * x.x;
            acc[a][1] += w[a] * x.y;
            acc[a][2] += w[a] * x.z;
            acc[a][3] += w[a] * x.w;
        }
    }

    // combine the two l-parity halves in LDS, then one atomic set per element
    __shared__ float comb[128][16];
    if (ls == 1) {
#pragma unroll
        for (int a = 0; a < 4; ++a)
#pragma unroll
            for (int e = 0; e < 4; ++e) comb[hi][a * 4 + e] = acc[a][e];
    }
    __syncthreads();
    if (ls == 0) {
#pragma unroll
        for (int a = 0; a < 4; ++a)
#pragma unroll
            for (int e = 0; e < 4; ++e) {
                const float v = acc[a][e] + comb[hi][a * 4 + e];
                atomicAdd(&S[a * (NH * NB) + (hi * 4 + e) * NB + b], v);
            }
    }
}

// ---------------------------------------------------------------------------
// K2: Vc_t[k][b] = sum_h Wtu[k,h]*S_ca[h][b] + Wtl[k,h]*S_cb[h][b]
//     Vd_t[k][b] = sum_h Wtu[k,h]*S_da[h][b] + Wtl[k,h]*S_db[h][b]
// One wave per k; lane = b. W loads wave-uniform (broadcast), S coalesced.
// ---------------------------------------------------------------------------
__global__ __launch_bounds__(256) void k2_vt(
    const float* __restrict__ Wtu, const float* __restrict__ Wtl,
    const float* __restrict__ S,
    float* __restrict__ Vc, float* __restrict__ Vd)
{
    const int lane = threadIdx.x & 63;
    const int k    = blockIdx.x * 4 + (threadIdx.x >> 6);
    const float* __restrict__ Sca = S;
    const float* __restrict__ Scb = S + NH * NB;
    const float* __restrict__ Sda = S + 2 * NH * NB;
    const float* __restrict__ Sdb = S + 3 * NH * NB;
    const float* __restrict__ wur = Wtu + (size_t)k * NH;
    const float* __restrict__ wlr = Wtl + (size_t)k * NH;

    float vc = 0.f, vd = 0.f;
#pragma unroll 8
    for (int h = 0; h < NH; ++h) {
        const float wu = wur[h], wl = wlr[h];
        const int o = h * NB + lane;
        vc += wu * Sca[o] + wl * Scb[o];
        vd += wu * Sda[o] + wl * Sdb[o];
    }
    Vc[k * NB + lane] = vc;
    Vd[k * NB + lane] = vd;
}

// ---------------------------------------------------------------------------
// K3: logits_t[j][b] = sum_k Wsu[j,k]*Vc_t[k][b] + Wsl[j,k]*Vd_t[k][b] + usr[j]
//     usr[j] = sum_k Wih[j,k] * h0[k]   (folded into same loop; wave-uniform)
// ---------------------------------------------------------------------------
__global__ __launch_bounds__(256) void k3_logits(
    const float* __restrict__ Wsu, const float* __restrict__ Wsl,
    const float* __restrict__ Wih, const float* __restrict__ h0,
    const float* __restrict__ Vc, const float* __restrict__ Vd,
    float* __restrict__ lg)
{
    const int lane = threadIdx.x & 63;
    const int j    = blockIdx.x * 4 + (threadIdx.x >> 6);
    const float* __restrict__ su = Wsu + (size_t)j * NH;
    const float* __restrict__ sl = Wsl + (size_t)j * NH;
    const float* __restrict__ ih = Wih + (size_t)j * NH;

    float s = 0.f, usr = 0.f;
#pragma unroll 8
    for (int k = 0; k < NH; ++k) {
        const float a = su[k], c = sl[k];
        const int o = k * NB + lane;
        s   += a * Vc[o] + c * Vd[o];
        usr += ih[k] * h0[k];
    }
    lg[j * NB + lane] = s + usr;
}

// ---------------------------------------------------------------------------
// K4: per-batch softmax over H. grid = NB, block = 512 (thread j).
// ---------------------------------------------------------------------------
__global__ __launch_bounds__(512) void k4_softmax(
    const float* __restrict__ lg, float* __restrict__ out)
{
    const int b = blockIdx.x;
    const int j = threadIdx.x;
    __shared__ float sd[512];

    const float v = lg[j * NB + b];
    sd[j] = v;
    __syncthreads();
    for (int s = 256; s > 0; s >>= 1) {
        if (j < s) sd[j] = fmaxf(sd[j], sd[j + s]);
        __syncthreads();
    }
    const float m = sd[0];
    __syncthreads();
    const float e = expf(v - m);
    sd[j] = e;
    __syncthreads();
    for (int s = 256; s > 0; s >>= 1) {
        if (j < s) sd[j] += sd[j + s];
        __syncthreads();
    }
    const float denom = sd[0];
    out[b * NH + j] = e / denom;
}

extern "C" void kernel_launch(void* const* d_in, const int* in_sizes, int n_in,
                              void* d_out, int out_size, void* d_ws, size_t ws_size,
                              hipStream_t stream)
{
    const float* td_u = (const float*)d_in[0];
    const float* td_l = (const float*)d_in[1];
    const float* ld_u = (const float*)d_in[2];
    const float* ld_l = (const float*)d_in[3];
    const int*   cloc = (const int*)d_in[4];
    const int*   llen = (const int*)d_in[5];
    const float* Wih  = (const float*)d_in[6];
    const float* Wtu  = (const float*)d_in[7];
    const float* Wtl  = (const float*)d_in[8];
    const float* Wsu  = (const float*)d_in[9];
    const float* Wsl  = (const float*)d_in[10];
    const float* h0   = (const float*)d_in[11];
    const float* locw = (const float*)d_in[12];

    float* S  = (float*)d_ws;              // 4*NH*NB
    float* Vc = S  + 4 * NH * NB;          // NH*NB
    float* Vd = Vc + NH * NB;              // NH*NB
    float* lg = Vd + NH * NB;              // NH*NB
    float* out = (float*)d_out;

    hipMemsetAsync(S, 0, (size_t)4 * NH * NB * sizeof(float), stream);

    k1_gather<<<dim3(NL / 64, NB), 256, 0, stream>>>(
        td_u, td_l, ld_u, ld_l, cloc, llen, locw, S);
    k2_vt<<<NH / 4, 256, 0, stream>>>(Wtu, Wtl, S, Vc, Vd);
    k3_logits<<<NH / 4, 256, 0, stream>>>(Wsu, Wsl, Wih, h0, Vc, Vd, lg);
    k4_softmax<<<NB, 512, 0, stream>>>(lg, out);
}

// Round 2
// 363.127 us; speedup vs baseline: 1.3154x; 1.3154x over previous
//
#include <hip/hip_runtime.h>
#include <math.h>

// Problem constants (reference: B=64, L=512, H=512, LOC_SIZE=100000)
constexpr int NB = 64;
constexpr int NL = 512;
constexpr int NH = 512;
#define EPSV 1e-9f

// Workspace layout (floats):
//   S   : 4 * NH * NB   (S_t[arr][h][b], arr = {ca, cb, da, db})  -- zeroed each launch
//   Vc  : NH * NB       (Vc_t[k][b])
//   Vd  : NH * NB       (Vd_t[k][b])
//   lg  : NH * NB       (logits_t[j][b])

// ---------------------------------------------------------------------------
// K1: masked, coefficient-weighted gather-reduce over L.
// grid = (NL/32, NB), block = 256. Thread (hi, ls): h-range hi*4..hi*4+3,
// l stride 2 starting at l0+ls. float4 row loads are coalesced (1 KB/wave).
// 1024 blocks = 16 waves/CU for gather-latency hiding.
// ---------------------------------------------------------------------------
__global__ __launch_bounds__(256) void k1_gather(
    const float* __restrict__ td_u, const float* __restrict__ td_l,
    const float* __restrict__ ld_u, const float* __restrict__ ld_l,
    const int* __restrict__ cur_loc, const int* __restrict__ loc_len,
    const float* __restrict__ locw, float* __restrict__ S)
{
    const int b   = blockIdx.y;
    const int len = loc_len[b];
    const int l0  = blockIdx.x * 32;
    if (l0 >= len) return;
    const int l1  = min(l0 + 32, len);

    const int tid = threadIdx.x;
    const int hi  = tid & 127;   // h-group index (4 floats each)
    const int ls  = tid >> 7;    // 0 or 1: which l parity this thread handles

    float acc[4][4];
#pragma unroll
    for (int a = 0; a < 4; ++a)
#pragma unroll
        for (int e = 0; e < 4; ++e) acc[a][e] = 0.f;

#pragma unroll 4
    for (int l = l0 + ls; l < l1; l += 2) {
        const int off = b * NL + l;
        const float tu = td_u[off], tl = td_l[off];
        const float lu = ld_u[off], ll = ld_l[off];
        const float rt = 1.f / (tu + tl + EPSV);
        const float rl = 1.f / (lu + ll + EPSV);
        const float a_ = tu * rt, b_ = tl * rt;
        const float c_ = lu * rl, d_ = ll * rl;
        const float w[4] = { c_ * a_, c_ * b_, d_ * a_, d_ * b_ };
        const int idx = cur_loc[off];
        const float4 x = *(const float4*)(locw + (size_t)idx * NH + hi * 4);
#pragma unroll
        for (int a = 0; a < 4; ++a) {
            acc[a][0] += w[a] * x.x;
            acc[a][1] += w[a] * x.y;
            acc[a][2] += w[a] * x.z;
            acc[a][3] += w[a] * x.w;
        }
    }

    // combine the two l-parity halves in LDS, then one atomic per element
    __shared__ float comb[128][16];
    if (ls == 1) {
#pragma unroll
        for (int a = 0; a < 4; ++a)
#pragma unroll
            for (int e = 0; e < 4; ++e) comb[hi][a * 4 + e] = acc[a][e];
    }
    __syncthreads();
    if (ls == 0) {
#pragma unroll
        for (int a = 0; a < 4; ++a)
#pragma unroll
            for (int e = 0; e < 4; ++e) {
                const float v = acc[a][e] + comb[hi][a * 4 + e];
                atomicAdd(&S[a * (NH * NB) + (hi * 4 + e) * NB + b], v);
            }
    }
}

// ---------------------------------------------------------------------------
// K2: Vc_t[j][b] = sum_h Wtu[j,h]*S_ca[h][b] + Wtl[j,h]*S_cb[h][b]
//     Vd_t[j][b] = sum_h Wtu[j,h]*S_da[h][b] + Wtl[j,h]*S_db[h][b]
// One block per j (512 blocks, 8 waves/CU). W rows staged in LDS (coalesced).
// K split across the block's 4 waves (128 h each); lane = b so S reads are
// coalesced 256 B. LDS tree-combine at the end.
// ---------------------------------------------------------------------------
__global__ __launch_bounds__(256) void k2_vt(
    const float* __restrict__ Wtu, const float* __restrict__ Wtl,
    const float* __restrict__ S,
    float* __restrict__ Vc, float* __restrict__ Vd)
{
    const int j   = blockIdx.x;
    const int tid = threadIdx.x;

    __shared__ float wu_s[NH];
    __shared__ float wl_s[NH];
    __shared__ float comb[4][2][NB];

    // stage weight rows (512 floats each) with coalesced float2 loads
    {
        const float2 va = ((const float2*)(Wtu + (size_t)j * NH))[tid];
        const float2 vb = ((const float2*)(Wtl + (size_t)j * NH))[tid];
        ((float2*)wu_s)[tid] = va;
        ((float2*)wl_s)[tid] = vb;
    }
    __syncthreads();

    const int w    = tid >> 6;
    const int lane = tid & 63;
    const float* __restrict__ Sca = S;
    const float* __restrict__ Scb = S + NH * NB;
    const float* __restrict__ Sda = S + 2 * NH * NB;
    const float* __restrict__ Sdb = S + 3 * NH * NB;

    float vc0 = 0.f, vc1 = 0.f, vd0 = 0.f, vd1 = 0.f;
    const int hbeg = w * 128;
#pragma unroll 8
    for (int h = hbeg; h < hbeg + 128; h += 2) {
        const float wuA = wu_s[h],     wlA = wl_s[h];
        const float wuB = wu_s[h + 1], wlB = wl_s[h + 1];
        const int oA = h * NB + lane;
        const int oB = oA + NB;
        vc0 += wuA * Sca[oA] + wlA * Scb[oA];
        vd0 += wuA * Sda[oA] + wlA * Sdb[oA];
        vc1 += wuB * Sca[oB] + wlB * Scb[oB];
        vd1 += wuB * Sda[oB] + wlB * Sdb[oB];
    }
    comb[w][0][lane] = vc0 + vc1;
    comb[w][1][lane] = vd0 + vd1;
    __syncthreads();

    if (tid < NB) {
        Vc[j * NB + tid] = comb[0][0][tid] + comb[1][0][tid]
                         + comb[2][0][tid] + comb[3][0][tid];
    } else if (tid < 2 * NB) {
        const int ln = tid - NB;
        Vd[j * NB + ln] = comb[0][1][ln] + comb[1][1][ln]
                        + comb[2][1][ln] + comb[3][1][ln];
    }
}

// ---------------------------------------------------------------------------
// K3: lg_t[j][b] = sum_k Wsu[j,k]*Vc[k][b] + Wsl[j,k]*Vd[k][b] + usr[j]
//     usr[j] = sum_k Wih[j,k]*h0[k], folded into the same K-split loop.
// Same structure as K2.
// ---------------------------------------------------------------------------
__global__ __launch_bounds__(256) void k3_logits(
    const float* __restrict__ Wsu, const float* __restrict__ Wsl,
    const float* __restrict__ Wih, const float* __restrict__ h0p,
    const float* __restrict__ Vc, const float* __restrict__ Vd,
    float* __restrict__ lg)
{
    const int j   = blockIdx.x;
    const int tid = threadIdx.x;

    __shared__ float su_s[NH];
    __shared__ float sl_s[NH];
    __shared__ float ih_s[NH];
    __shared__ float h0_s[NH];
    __shared__ float comb[4][64];
    __shared__ float comb_u[4];

    {
        const float2 va = ((const float2*)(Wsu + (size_t)j * NH))[tid];
        const float2 vb = ((const float2*)(Wsl + (size_t)j * NH))[tid];
        const float2 vi = ((const float2*)(Wih + (size_t)j * NH))[tid];
        const float2 vh = ((const float2*)h0p)[tid];
        ((float2*)su_s)[tid] = va;
        ((float2*)sl_s)[tid] = vb;
        ((float2*)ih_s)[tid] = vi;
        ((float2*)h0_s)[tid] = vh;
    }
    __syncthreads();

    const int w    = tid >> 6;
    const int lane = tid & 63;

    float s0 = 0.f, s1 = 0.f, u = 0.f;
    const int kbeg = w * 128;
#pragma unroll 8
    for (int k = kbeg; k < kbeg + 128; k += 2) {
        const float aA = su_s[k],     cA = sl_s[k];
        const float aB = su_s[k + 1], cB = sl_s[k + 1];
        const int oA = k * NB + lane;
        const int oB = oA + NB;
        s0 += aA * Vc[oA] + cA * Vd[oA];
        s1 += aB * Vc[oB] + cB * Vd[oB];
        u  += ih_s[k] * h0_s[k] + ih_s[k + 1] * h0_s[k + 1];
    }
    comb[w][lane] = s0 + s1;
    if (lane == 0) comb_u[w] = u;
    __syncthreads();

    if (tid < NB) {
        const float s = comb[0][tid] + comb[1][tid] + comb[2][tid] + comb[3][tid];
        const float usr = comb_u[0] + comb_u[1] + comb_u[2] + comb_u[3];
        lg[j * NB + tid] = s + usr;
    }
}

// ---------------------------------------------------------------------------
// K4: per-batch softmax over H. grid = NB, block = 512 (thread j).
// ---------------------------------------------------------------------------
__global__ __launch_bounds__(512) void k4_softmax(
    const float* __restrict__ lg, float* __restrict__ out)
{
    const int b = blockIdx.x;
    const int j = threadIdx.x;
    __shared__ float sd[512];

    const float v = lg[j * NB + b];
    sd[j] = v;
    __syncthreads();
    for (int s = 256; s > 0; s >>= 1) {
        if (j < s) sd[j] = fmaxf(sd[j], sd[j + s]);
        __syncthreads();
    }
    const float m = sd[0];
    __syncthreads();
    const float e = expf(v - m);
    sd[j] = e;
    __syncthreads();
    for (int s = 256; s > 0; s >>= 1) {
        if (j < s) sd[j] += sd[j + s];
        __syncthreads();
    }
    const float denom = sd[0];
    out[b * NH + j] = e / denom;
}

extern "C" void kernel_launch(void* const* d_in, const int* in_sizes, int n_in,
                              void* d_out, int out_size, void* d_ws, size_t ws_size,
                              hipStream_t stream)
{
    const float* td_u = (const float*)d_in[0];
    const float* td_l = (const float*)d_in[1];
    const float* ld_u = (const float*)d_in[2];
    const float* ld_l = (const float*)d_in[3];
    const int*   cloc = (const int*)d_in[4];
    const int*   llen = (const int*)d_in[5];
    const float* Wih  = (const float*)d_in[6];
    const float* Wtu  = (const float*)d_in[7];
    const float* Wtl  = (const float*)d_in[8];
    const float* Wsu  = (const float*)d_in[9];
    const float* Wsl  = (const float*)d_in[10];
    const float* h0   = (const float*)d_in[11];
    const float* locw = (const float*)d_in[12];

    float* S  = (float*)d_ws;              // 4*NH*NB
    float* Vc = S  + 4 * NH * NB;          // NH*NB
    float* Vd = Vc + NH * NB;              // NH*NB
    float* lg = Vd + NH * NB;              // NH*NB
    float* out = (float*)d_out;

    hipMemsetAsync(S, 0, (size_t)4 * NH * NB * sizeof(float), stream);

    k1_gather<<<dim3(NL / 32, NB), 256, 0, stream>>>(
        td_u, td_l, ld_u, ld_l, cloc, llen, locw, S);
    k2_vt<<<NH, 256, 0, stream>>>(Wtu, Wtl, S, Vc, Vd);
    k3_logits<<<NH, 256, 0, stream>>>(Wsu, Wsl, Wih, h0, Vc, Vd, lg);
    k4_softmax<<<NB, 512, 0, stream>>>(lg, out);
}

// Round 3
// 311.051 us; speedup vs baseline: 1.5356x; 1.1674x over previous
//
#include <hip/hip_runtime.h>
#include <math.h>

// Problem constants (reference: B=64, L=512, H=512, LOC_SIZE=100000)
constexpr int NB = 64;
constexpr int NL = 512;
constexpr int NH = 512;
#define EPSV 1e-9f

// Workspace layout (floats):
//   S   : 4 * NH * NB   (S_t[arr][h][b], arr = {ca, cb, da, db})
//   Vc  : NH * NB       (Vc_t[k][b])
//   Vd  : NH * NB       (Vd_t[k][b])
//   lg  : NH * NB       (logits_t[j][b])
// S is FULLY written by k1 (no memset, no atomics).

// ---------------------------------------------------------------------------
// K1: masked, coefficient-weighted gather-reduce over L. Atomic-free.
// grid = (NH/32, NB) = (16, 64) blocks, 256 threads.
// Thread (hi = tid&7, ls = tid>>3): h-range hc*32 + hi*4 .. +3, l stride 32.
// Gathers: 8 lanes x float4 = 128 B contiguous per row per l. Register
// accumulate, shuffle-reduce the 8 ls-groups per wave, LDS-combine the
// 4 waves, direct store (each S element owned by exactly one block).
// ---------------------------------------------------------------------------
__global__ __launch_bounds__(256) void k1_gather(
    const float* __restrict__ td_u, const float* __restrict__ td_l,
    const float* __restrict__ ld_u, const float* __restrict__ ld_l,
    const int* __restrict__ cur_loc, const int* __restrict__ loc_len,
    const float* __restrict__ locw, float* __restrict__ S)
{
    const int hc  = blockIdx.x;       // h-chunk: 32 h each
    const int b   = blockIdx.y;
    const int len = loc_len[b];
    const int tid = threadIdx.x;
    const int hi  = tid & 7;          // h-group (4 floats) within chunk
    const int ls  = tid >> 3;         // l-slice 0..31
    const int hbase = hc * 32 + hi * 4;

    float acc[4][4];
#pragma unroll
    for (int a = 0; a < 4; ++a)
#pragma unroll
        for (int e = 0; e < 4; ++e) acc[a][e] = 0.f;

#pragma unroll 4
    for (int l = ls; l < len; l += 32) {
        const int off = b * NL + l;
        const float tu = td_u[off], tl = td_l[off];
        const float lu = ld_u[off], ll = ld_l[off];
        const float rt = 1.f / (tu + tl + EPSV);
        const float rl = 1.f / (lu + ll + EPSV);
        const float a_ = tu * rt, b_ = tl * rt;
        const float c_ = lu * rl, d_ = ll * rl;
        const float w[4] = { c_ * a_, c_ * b_, d_ * a_, d_ * b_ };
        const int idx = cur_loc[off];
        const float4 x = *(const float4*)(locw + (size_t)idx * NH + hbase);
#pragma unroll
        for (int a = 0; a < 4; ++a) {
            acc[a][0] += w[a] * x.x;
            acc[a][1] += w[a] * x.y;
            acc[a][2] += w[a] * x.z;
            acc[a][3] += w[a] * x.w;
        }
    }

    // reduce the 8 ls-groups within each wave (lane stride 8)
#pragma unroll
    for (int a = 0; a < 4; ++a)
#pragma unroll
        for (int e = 0; e < 4; ++e) {
            float x = acc[a][e];
            x += __shfl_down(x, 32);
            x += __shfl_down(x, 16);
            x += __shfl_down(x, 8);
            acc[a][e] = x;
        }

    __shared__ float red[4][8][17];   // [wave][hi][v], padded vs bank conflicts
    const int wv   = tid >> 6;
    const int lane = tid & 63;
    if (lane < 8) {
#pragma unroll
        for (int a = 0; a < 4; ++a)
#pragma unroll
            for (int e = 0; e < 4; ++e) red[wv][hi][a * 4 + e] = acc[a][e];
    }
    __syncthreads();

    // combine 4 waves and store: 128 threads, one element each
    if (tid < 128) {
        const int hi2 = tid & 7;
        const int v   = tid >> 3;     // 0..15
        const float s = red[0][hi2][v] + red[1][hi2][v]
                      + red[2][hi2][v] + red[3][hi2][v];
        const int a = v >> 2, e = v & 3;
        S[a * (NH * NB) + (hc * 32 + hi2 * 4 + e) * NB + b] = s;
    }
}

// ---------------------------------------------------------------------------
// K2: Vc_t[j][b] = sum_h Wtu[j,h]*S_ca[h][b] + Wtl[j,h]*S_cb[h][b]
//     Vd_t[j][b] = sum_h Wtu[j,h]*S_da[h][b] + Wtl[j,h]*S_db[h][b]
// One block per j (512 blocks, 8 waves/CU). W rows staged in LDS (coalesced).
// K split across the block's 4 waves (128 h each); lane = b so S reads are
// coalesced 256 B. LDS tree-combine at the end.
// ---------------------------------------------------------------------------
__global__ __launch_bounds__(256) void k2_vt(
    const float* __restrict__ Wtu, const float* __restrict__ Wtl,
    const float* __restrict__ S,
    float* __restrict__ Vc, float* __restrict__ Vd)
{
    const int j   = blockIdx.x;
    const int tid = threadIdx.x;

    __shared__ float wu_s[NH];
    __shared__ float wl_s[NH];
    __shared__ float comb[4][2][NB];

    {
        const float2 va = ((const float2*)(Wtu + (size_t)j * NH))[tid];
        const float2 vb = ((const float2*)(Wtl + (size_t)j * NH))[tid];
        ((float2*)wu_s)[tid] = va;
        ((float2*)wl_s)[tid] = vb;
    }
    __syncthreads();

    const int w    = tid >> 6;
    const int lane = tid & 63;
    const float* __restrict__ Sca = S;
    const float* __restrict__ Scb = S + NH * NB;
    const float* __restrict__ Sda = S + 2 * NH * NB;
    const float* __restrict__ Sdb = S + 3 * NH * NB;

    float vc0 = 0.f, vc1 = 0.f, vd0 = 0.f, vd1 = 0.f;
    const int hbeg = w * 128;
#pragma unroll 8
    for (int h = hbeg; h < hbeg + 128; h += 2) {
        const float wuA = wu_s[h],     wlA = wl_s[h];
        const float wuB = wu_s[h + 1], wlB = wl_s[h + 1];
        const int oA = h * NB + lane;
        const int oB = oA + NB;
        vc0 += wuA * Sca[oA] + wlA * Scb[oA];
        vd0 += wuA * Sda[oA] + wlA * Sdb[oA];
        vc1 += wuB * Sca[oB] + wlB * Scb[oB];
        vd1 += wuB * Sda[oB] + wlB * Sdb[oB];
    }
    comb[w][0][lane] = vc0 + vc1;
    comb[w][1][lane] = vd0 + vd1;
    __syncthreads();

    if (tid < NB) {
        Vc[j * NB + tid] = comb[0][0][tid] + comb[1][0][tid]
                         + comb[2][0][tid] + comb[3][0][tid];
    } else if (tid < 2 * NB) {
        const int ln = tid - NB;
        Vd[j * NB + ln] = comb[0][1][ln] + comb[1][1][ln]
                        + comb[2][1][ln] + comb[3][1][ln];
    }
}

// ---------------------------------------------------------------------------
// K3: lg_t[j][b] = sum_k Wsu[j,k]*Vc[k][b] + Wsl[j,k]*Vd[k][b] + usr[j]
//     usr[j] = sum_k Wih[j,k]*h0[k], folded into the same K-split loop.
// ---------------------------------------------------------------------------
__global__ __launch_bounds__(256) void k3_logits(
    const float* __restrict__ Wsu, const float* __restrict__ Wsl,
    const float* __restrict__ Wih, const float* __restrict__ h0p,
    const float* __restrict__ Vc, const float* __restrict__ Vd,
    float* __restrict__ lg)
{
    const int j   = blockIdx.x;
    const int tid = threadIdx.x;

    __shared__ float su_s[NH];
    __shared__ float sl_s[NH];
    __shared__ float ih_s[NH];
    __shared__ float h0_s[NH];
    __shared__ float comb[4][64];
    __shared__ float comb_u[4];

    {
        const float2 va = ((const float2*)(Wsu + (size_t)j * NH))[tid];
        const float2 vb = ((const float2*)(Wsl + (size_t)j * NH))[tid];
        const float2 vi = ((const float2*)(Wih + (size_t)j * NH))[tid];
        const float2 vh = ((const float2*)h0p)[tid];
        ((float2*)su_s)[tid] = va;
        ((float2*)sl_s)[tid] = vb;
        ((float2*)ih_s)[tid] = vi;
        ((float2*)h0_s)[tid] = vh;
    }
    __syncthreads();

    const int w    = tid >> 6;
    const int lane = tid & 63;

    float s0 = 0.f, s1 = 0.f, u = 0.f;
    const int kbeg = w * 128;
#pragma unroll 8
    for (int k = kbeg; k < kbeg + 128; k += 2) {
        const float aA = su_s[k],     cA = sl_s[k];
        const float aB = su_s[k + 1], cB = sl_s[k + 1];
        const int oA = k * NB + lane;
        const int oB = oA + NB;
        s0 += aA * Vc[oA] + cA * Vd[oA];
        s1 += aB * Vc[oB] + cB * Vd[oB];
        u  += ih_s[k] * h0_s[k] + ih_s[k + 1] * h0_s[k + 1];
    }
    comb[w][lane] = s0 + s1;
    if (lane == 0) comb_u[w] = u;
    __syncthreads();

    if (tid < NB) {
        const float s = comb[0][tid] + comb[1][tid] + comb[2][tid] + comb[3][tid];
        const float usr = comb_u[0] + comb_u[1] + comb_u[2] + comb_u[3];
        lg[j * NB + tid] = s + usr;
    }
}

// ---------------------------------------------------------------------------
// K4: per-batch softmax over H. grid = NB, block = 512 (thread j).
// ---------------------------------------------------------------------------
__global__ __launch_bounds__(512) void k4_softmax(
    const float* __restrict__ lg, float* __restrict__ out)
{
    const int b = blockIdx.x;
    const int j = threadIdx.x;
    __shared__ float sd[512];

    const float v = lg[j * NB + b];
    sd[j] = v;
    __syncthreads();
    for (int s = 256; s > 0; s >>= 1) {
        if (j < s) sd[j] = fmaxf(sd[j], sd[j + s]);
        __syncthreads();
    }
    const float m = sd[0];
    __syncthreads();
    const float e = expf(v - m);
    sd[j] = e;
    __syncthreads();
    for (int s = 256; s > 0; s >>= 1) {
        if (j < s) sd[j] += sd[j + s];
        __syncthreads();
    }
    const float denom = sd[0];
    out[b * NH + j] = e / denom;
}

extern "C" void kernel_launch(void* const* d_in, const int* in_sizes, int n_in,
                              void* d_out, int out_size, void* d_ws, size_t ws_size,
                              hipStream_t stream)
{
    const float* td_u = (const float*)d_in[0];
    const float* td_l = (const float*)d_in[1];
    const float* ld_u = (const float*)d_in[2];
    const float* ld_l = (const float*)d_in[3];
    const int*   cloc = (const int*)d_in[4];
    const int*   llen = (const int*)d_in[5];
    const float* Wih  = (const float*)d_in[6];
    const float* Wtu  = (const float*)d_in[7];
    const float* Wtl  = (const float*)d_in[8];
    const float* Wsu  = (const float*)d_in[9];
    const float* Wsl  = (const float*)d_in[10];
    const float* h0   = (const float*)d_in[11];
    const float* locw = (const float*)d_in[12];

    float* S  = (float*)d_ws;              // 4*NH*NB, fully written by k1
    float* Vc = S  + 4 * NH * NB;          // NH*NB
    float* Vd = Vc + NH * NB;              // NH*NB
    float* lg = Vd + NH * NB;              // NH*NB
    float* out = (float*)d_out;

    k1_gather<<<dim3(NH / 32, NB), 256, 0, stream>>>(
        td_u, td_l, ld_u, ld_l, cloc, llen, locw, S);
    k2_vt<<<NH, 256, 0, stream>>>(Wtu, Wtl, S, Vc, Vd);
    k3_logits<<<NH, 256, 0, stream>>>(Wsu, Wsl, Wih, h0, Vc, Vd, lg);
    k4_softmax<<<NB, 512, 0, stream>>>(lg, out);
}